// Round 1
// baseline (959.357 us; speedup 1.0000x reference)
//
#include <hip/hip_runtime.h>
#include <hip/hip_bf16.h>
#include <float.h>

#define BATCH 8
#define CDIM 64
#define NPTS 4096
#define KNN 20
#define BN_EPS 1e-5f
#define NEG_SLOPE 0.2f

// ---------------------------------------------------------------------------
// K1: transpose x [B,C,N] -> xt [B,N,C], and sq[b,n] = sum_c x^2
// ---------------------------------------------------------------------------
__global__ void k_transpose_sq(const float* __restrict__ x,
                               float* __restrict__ xt,
                               float* __restrict__ sq) {
    int gid = blockIdx.x * 256 + threadIdx.x;     // [0, B*N)
    int b = gid >> 12;
    int n = gid & (NPTS - 1);
    const float* xb = x + (size_t)b * CDIM * NPTS;
    float acc = 0.f;
    float4* xtv = (float4*)(xt + (((size_t)gid) << 6));
    #pragma unroll
    for (int cg = 0; cg < 4; ++cg) {
        float v[16];
        #pragma unroll
        for (int j = 0; j < 16; ++j) {
            v[j] = xb[(cg * 16 + j) * NPTS + n];   // coalesced across n
            acc = fmaf(v[j], v[j], acc);
        }
        #pragma unroll
        for (int q = 0; q < 4; ++q)
            xtv[cg * 4 + q] = make_float4(v[q*4], v[q*4+1], v[q*4+2], v[q*4+3]);
    }
    sq[gid] = acc;
}

// ---------------------------------------------------------------------------
// K2: p = W1 @ x, z = (W2-W1) @ x, stored transposed: pt/zt [B,N,64]
// block: 64 n x 64 o; wave w does o in [16w,16w+16), lane = n
// ---------------------------------------------------------------------------
__global__ void k_pz(const float* __restrict__ xt, const float* __restrict__ W,
                     float* __restrict__ pt, float* __restrict__ zt) {
    int b  = blockIdx.x >> 6;
    int n0 = (blockIdx.x & 63) << 6;
    int lane = threadIdx.x & 63;
    int w = threadIdx.x >> 6;
    int n = n0 + lane;
    size_t rowoff = ((size_t)(b * NPTS + n)) << 6;
    const float4* xrow = (const float4*)(xt + rowoff);
    float acc1[16], acc2[16];
    #pragma unroll
    for (int i = 0; i < 16; ++i) { acc1[i] = 0.f; acc2[i] = 0.f; }
    #pragma unroll
    for (int cg = 0; cg < 4; ++cg) {
        float xv[16];
        #pragma unroll
        for (int q = 0; q < 4; ++q) {
            float4 t = xrow[cg * 4 + q];
            xv[q*4] = t.x; xv[q*4+1] = t.y; xv[q*4+2] = t.z; xv[q*4+3] = t.w;
        }
        #pragma unroll
        for (int oi = 0; oi < 16; ++oi) {
            int o = (w << 4) + oi;
            const float* wr = W + o * 128 + cg * 16;
            float a1 = acc1[oi], a2 = acc2[oi];
            #pragma unroll
            for (int j = 0; j < 16; ++j) {
                a1 = fmaf(wr[j],      xv[j], a1);
                a2 = fmaf(wr[64 + j], xv[j], a2);
            }
            acc1[oi] = a1; acc2[oi] = a2;
        }
    }
    float4* pv = (float4*)(pt + rowoff + (w << 4));
    float4* zv = (float4*)(zt + rowoff + (w << 4));
    #pragma unroll
    for (int q = 0; q < 4; ++q) {
        pv[q] = make_float4(acc1[q*4], acc1[q*4+1], acc1[q*4+2], acc1[q*4+3]);
        zv[q] = make_float4(acc2[q*4]   - acc1[q*4],
                            acc2[q*4+1] - acc1[q*4+1],
                            acc2[q*4+2] - acc1[q*4+2],
                            acc2[q*4+3] - acc1[q*4+3]);
    }
}

// ---------------------------------------------------------------------------
// K3: kNN. block = (b, 16 rows); wave handles 4 rows x all 4096 candidates.
// Candidates staged 64-at-a-time in LDS (lane = candidate); row vectors read
// via wave-uniform loads (readfirstlane -> s_load). Top-20 per row kept in
// lane registers (lanes 0..19 hold the sorted list), ballot-driven insertion.
// ---------------------------------------------------------------------------
__device__ __forceinline__ void topk_update(float d, int gi, float& dl, int& il,
                                            float& tau, int lane) {
    unsigned long long mask = __ballot(d < tau);
    while (mask) {
        int s = __ffsll(mask) - 1;
        float ds = __shfl(d, s);
        int   is = __shfl(gi, s);
        unsigned long long gt = __ballot(ds < dl);   // suffix of sorted list
        int pos = __ffsll(gt) - 1;                   // insertion point <= 19
        float pd = __shfl_up(dl, 1);
        int   pi = __shfl_up(il, 1);
        if (lane >= pos && lane < KNN) {
            if (lane == pos) { dl = ds; il = is; }
            else             { dl = pd; il = pi; }
        }
        tau = __shfl(dl, KNN - 1);
        mask &= ~(1ull << s);
        mask &= __ballot(d < tau);
    }
}

__global__ void __launch_bounds__(256) k_knn(const float* __restrict__ x,
                                             const float* __restrict__ xt,
                                             const float* __restrict__ sq,
                                             int* __restrict__ idxout) {
    __shared__ float xs[64][64];
    __shared__ float sqs[64];
    int b  = blockIdx.x >> 8;            // 256 blocks per batch
    int n0 = (blockIdx.x & 255) << 4;    // 16 rows per block
    int lane = threadIdx.x & 63;
    int w = threadIdx.x >> 6;
    int row0 = n0 + (w << 2);            // this wave's 4 rows
    const float* xb = x + (size_t)b * CDIM * NPTS;

    // wave-uniform base into xt for the 4 row vectors
    int rbase = __builtin_amdgcn_readfirstlane((b * NPTS + row0) << 6);
    const float* rp = xt + rbase;

    float dl[4], tauv[4]; int il[4];
    #pragma unroll
    for (int r = 0; r < 4; ++r) { dl[r] = FLT_MAX; il[r] = 0; tauv[r] = FLT_MAX; }
    float sqrow[4];
    #pragma unroll
    for (int r = 0; r < 4; ++r) sqrow[r] = sq[b * NPTS + row0 + r];

    for (int chunk = 0; chunk < 64; ++chunk) {
        int m0 = chunk << 6;
        __syncthreads();
        #pragma unroll
        for (int i = 0; i < 16; ++i) {
            int id = i * 256 + threadIdx.x;
            int c = id >> 6, m = id & 63;
            xs[c][m] = xb[c * NPTS + m0 + m];     // coalesced
        }
        if (threadIdx.x < 64) sqs[threadIdx.x] = sq[b * NPTS + m0 + threadIdx.x];
        __syncthreads();

        float acc0 = 0.f, acc1 = 0.f, acc2 = 0.f, acc3 = 0.f;
        #pragma unroll
        for (int cg = 0; cg < 4; ++cg) {
            #pragma unroll
            for (int j = 0; j < 16; ++j) {
                int c = cg * 16 + j;
                float xv = xs[c][lane];
                acc0 = fmaf(rp[0 * 64 + c], xv, acc0);
                acc1 = fmaf(rp[1 * 64 + c], xv, acc1);
                acc2 = fmaf(rp[2 * 64 + c], xv, acc2);
                acc3 = fmaf(rp[3 * 64 + c], xv, acc3);
            }
        }
        float sv = sqs[lane];
        int gi = m0 + lane;
        float d0 = sqrow[0] + sv - 2.f * acc0;
        float d1 = sqrow[1] + sv - 2.f * acc1;
        float d2 = sqrow[2] + sv - 2.f * acc2;
        float d3 = sqrow[3] + sv - 2.f * acc3;
        topk_update(d0, gi, dl[0], il[0], tauv[0], lane);
        topk_update(d1, gi, dl[1], il[1], tauv[1], lane);
        topk_update(d2, gi, dl[2], il[2], tauv[2], lane);
        topk_update(d3, gi, dl[3], il[3], tauv[3], lane);
    }
    #pragma unroll
    for (int r = 0; r < 4; ++r)
        if (lane < KNN)
            idxout[(size_t)(b * NPTS + row0 + r) * KNN + lane] = il[r];
}

// ---------------------------------------------------------------------------
// K4: gather p columns per neighbor; per-(b,n) max/min/sum/sumsq over k;
// write tmax/tmin = (max/min_k p[idx]) + z; accumulate channel sums.
// lane = channel o (coalesced 256B gathers of pt columns).
// ---------------------------------------------------------------------------
__global__ void k_gather(const float* __restrict__ pt, const float* __restrict__ zt,
                         const int* __restrict__ idxin,
                         float* __restrict__ tmax, float* __restrict__ tmin,
                         float* __restrict__ S1, float* __restrict__ S2) {
    __shared__ float red1[4][64];
    __shared__ float red2[4][64];
    int b  = blockIdx.x >> 6;
    int n0 = (blockIdx.x & 63) << 6;
    int lane = threadIdx.x & 63;
    int w = threadIdx.x >> 6;
    float cs1 = 0.f, cs2 = 0.f;
    for (int i = 0; i < 16; ++i) {
        int n = n0 + (w << 4) + i;
        int base = b * NPTS + n;
        int ibase = __builtin_amdgcn_readfirstlane(base * KNN);
        const int* ip = idxin + ibase;
        float mx = -FLT_MAX, mn = FLT_MAX, s1 = 0.f, s2 = 0.f;
        #pragma unroll
        for (int k = 0; k < KNN; ++k) {
            int col = ip[k];                               // SGPR
            float v = pt[(((size_t)(b * NPTS + col)) << 6) + lane]; // coalesced
            mx = fmaxf(mx, v); mn = fminf(mn, v);
            s1 += v; s2 = fmaf(v, v, s2);
        }
        float z = zt[(((size_t)base) << 6) + lane];
        tmax[(((size_t)base) << 6) + lane] = mx + z;
        tmin[(((size_t)base) << 6) + lane] = mn + z;
        cs1 += s1 + (float)KNN * z;
        cs2 += s2 + 2.f * z * s1 + (float)KNN * z * z;
    }
    red1[w][lane] = cs1;
    red2[w][lane] = cs2;
    __syncthreads();
    if (threadIdx.x < 64) {
        float t1 = red1[0][lane] + red1[1][lane] + red1[2][lane] + red1[3][lane];
        float t2 = red2[0][lane] + red2[1][lane] + red2[2][lane] + red2[3][lane];
        atomicAdd(&S1[lane], t1);
        atomicAdd(&S2[lane], t2);
    }
}

// ---------------------------------------------------------------------------
// K5: finalize BN stats, affine + LeakyReLU, transpose to out [B,64,N].
// BN scale>=0 -> use tmax; scale<0 -> tmin (monotonicity of max over k).
// ---------------------------------------------------------------------------
__global__ void k_final(const float* __restrict__ tmax, const float* __restrict__ tmin,
                        const float* __restrict__ S1, const float* __restrict__ S2,
                        const float* __restrict__ gamma, const float* __restrict__ beta,
                        float* __restrict__ out) {
    __shared__ float smx[64][65];
    __shared__ float smn[64][65];
    int b  = blockIdx.x >> 6;
    int n0 = (blockIdx.x & 63) << 6;
    int lane = threadIdx.x & 63;
    int w = threadIdx.x >> 6;
    #pragma unroll
    for (int i = 0; i < 16; ++i) {
        int nl = (i << 2) + w;
        size_t off = (((size_t)(b * NPTS + n0 + nl)) << 6) + lane;
        smx[nl][lane] = tmax[off];
        smn[nl][lane] = tmin[off];
    }
    __syncthreads();
    const float inv_cnt = 1.0f / ((float)BATCH * NPTS * KNN);
    #pragma unroll
    for (int i = 0; i < 16; ++i) {
        int o = (i << 2) + w;
        float s1 = S1[o], s2 = S2[o];
        float mean = s1 * inv_cnt;
        float var = fmaf(-mean, mean, s2 * inv_cnt);
        float rs = rsqrtf(var + BN_EPS);
        float sc = gamma[o] * rs;
        float sh = beta[o] - mean * sc;
        float tv = (sc >= 0.f) ? smx[lane][o] : smn[lane][o];
        float y = fmaf(tv, sc, sh);
        y = (y >= 0.f) ? y : NEG_SLOPE * y;
        out[((size_t)(b * 64 + o)) * NPTS + n0 + lane] = y;
    }
}

// ---------------------------------------------------------------------------
extern "C" void kernel_launch(void* const* d_in, const int* in_sizes, int n_in,
                              void* d_out, int out_size, void* d_ws, size_t ws_size,
                              hipStream_t stream) {
    const float* x     = (const float*)d_in[0];   // [8,64,4096]
    const float* W     = (const float*)d_in[1];   // [64,128]
    const float* gamma = (const float*)d_in[2];   // [64]
    const float* beta  = (const float*)d_in[3];   // [64]
    float* out = (float*)d_out;                   // [8,64,4096]

    float* ws = (float*)d_ws;
    const size_t SECT = (size_t)BATCH * NPTS * 64;   // 2,097,152 floats
    float* xt   = ws;
    float* pt   = ws + SECT;
    float* zt   = ws + 2 * SECT;
    float* tmx  = ws + 3 * SECT;
    float* tmn  = ws + 4 * SECT;
    float* sq   = ws + 5 * SECT;                          // B*N floats
    int*   idx  = (int*)(ws + 5 * SECT + (size_t)BATCH * NPTS);
    float* S1   = ws + 5 * SECT + (size_t)BATCH * NPTS + (size_t)BATCH * NPTS * KNN;
    float* S2   = S1 + 64;
    // total ws use: ~44.7 MB

    hipMemsetAsync(S1, 0, 2 * 64 * sizeof(float), stream);
    k_transpose_sq<<<dim3((BATCH * NPTS) / 256), dim3(256), 0, stream>>>(x, xt, sq);
    k_pz<<<dim3(BATCH * (NPTS / 64)), dim3(256), 0, stream>>>(xt, W, pt, zt);
    k_knn<<<dim3(BATCH * (NPTS / 16)), dim3(256), 0, stream>>>(x, xt, sq, idx);
    k_gather<<<dim3(BATCH * (NPTS / 64)), dim3(256), 0, stream>>>(pt, zt, idx, tmx, tmn, S1, S2);
    k_final<<<dim3(BATCH * (NPTS / 64)), dim3(256), 0, stream>>>(tmx, tmn, S1, S2, gamma, beta, out);
}

// Round 3
// 885.274 us; speedup vs baseline: 1.0837x; 1.0837x over previous
//
#include <hip/hip_runtime.h>
#include <hip/hip_bf16.h>
#include <float.h>

#define BATCH 8
#define CDIM 64
#define NPTS 4096
#define KNN 20
#define KSEL 32
#define BN_EPS 1e-5f
#define NEG_SLOPE 0.2f

typedef __attribute__((ext_vector_type(8))) short short8;
typedef __attribute__((ext_vector_type(4))) float float4v;
typedef unsigned short ushort;
typedef unsigned int uint;

__device__ __forceinline__ ushort f2bf(float f) {
    uint u = __float_as_uint(f);
    u += 0x7FFF + ((u >> 16) & 1);            // round-to-nearest-even
    return (ushort)(u >> 16);
}
__device__ __forceinline__ float bf2f(ushort h) {
    return __uint_as_float(((uint)h) << 16);
}

// ---------------------------------------------------------------------------
// K1: x [B,C,N] -> xt [B,N,64] fp32, xh/xl [B,N,64] bf16 hi/lo split,
//     sq[b,n] = sum_c x^2 (fp32)
// ---------------------------------------------------------------------------
__global__ void k_prep(const float* __restrict__ x,
                       float* __restrict__ xt,
                       ushort* __restrict__ xh,
                       ushort* __restrict__ xl,
                       float* __restrict__ sq) {
    int gid = blockIdx.x * 256 + threadIdx.x;     // [0, B*N)
    int b = gid >> 12;
    int n = gid & (NPTS - 1);
    const float* xb = x + (size_t)b * CDIM * NPTS + n;
    float acc = 0.f;
    float4* xtv = (float4*)(xt + ((size_t)gid << 6));
    uint2* xhp = (uint2*)(xh + ((size_t)gid << 6));
    uint2* xlp = (uint2*)(xl + ((size_t)gid << 6));
    #pragma unroll
    for (int q = 0; q < 16; ++q) {
        float v[4];
        ushort h[4], l[4];
        #pragma unroll
        for (int j = 0; j < 4; ++j) {
            float t = xb[(q * 4 + j) * NPTS];     // coalesced across n
            v[j] = t;
            acc = fmaf(t, t, acc);
            h[j] = f2bf(t);
            l[j] = f2bf(t - bf2f(h[j]));
        }
        xtv[q] = make_float4(v[0], v[1], v[2], v[3]);
        uint2 ph, pl;
        ph.x = (uint)h[0] | ((uint)h[1] << 16);
        ph.y = (uint)h[2] | ((uint)h[3] << 16);
        pl.x = (uint)l[0] | ((uint)l[1] << 16);
        pl.y = (uint)l[2] | ((uint)l[3] << 16);
        xhp[q] = ph;
        xlp[q] = pl;
    }
    sq[gid] = acc;
}

// ---------------------------------------------------------------------------
// K2: p = W1 @ x, z = (W2-W1) @ x, stored transposed: pt/zt [B,N,64]
// ---------------------------------------------------------------------------
__global__ void k_pz(const float* __restrict__ xt, const float* __restrict__ W,
                     float* __restrict__ pt, float* __restrict__ zt) {
    int b  = blockIdx.x >> 6;
    int n0 = (blockIdx.x & 63) << 6;
    int lane = threadIdx.x & 63;
    int w = threadIdx.x >> 6;
    int n = n0 + lane;
    size_t rowoff = ((size_t)(b * NPTS + n)) << 6;
    const float4* xrow = (const float4*)(xt + rowoff);
    float acc1[16], acc2[16];
    #pragma unroll
    for (int i = 0; i < 16; ++i) { acc1[i] = 0.f; acc2[i] = 0.f; }
    #pragma unroll
    for (int cg = 0; cg < 4; ++cg) {
        float xv[16];
        #pragma unroll
        for (int q = 0; q < 4; ++q) {
            float4 t = xrow[cg * 4 + q];
            xv[q*4] = t.x; xv[q*4+1] = t.y; xv[q*4+2] = t.z; xv[q*4+3] = t.w;
        }
        #pragma unroll
        for (int oi = 0; oi < 16; ++oi) {
            int o = (w << 4) + oi;
            const float* wr = W + o * 128 + cg * 16;
            float a1 = acc1[oi], a2 = acc2[oi];
            #pragma unroll
            for (int j = 0; j < 16; ++j) {
                a1 = fmaf(wr[j],      xv[j], a1);
                a2 = fmaf(wr[64 + j], xv[j], a2);
            }
            acc1[oi] = a1; acc2[oi] = a2;
        }
    }
    float4* pv = (float4*)(pt + rowoff + (w << 4));
    float4* zv = (float4*)(zt + rowoff + (w << 4));
    #pragma unroll
    for (int q = 0; q < 4; ++q) {
        pv[q] = make_float4(acc1[q*4], acc1[q*4+1], acc1[q*4+2], acc1[q*4+3]);
        zv[q] = make_float4(acc2[q*4]   - acc1[q*4],
                            acc2[q*4+1] - acc1[q*4+1],
                            acc2[q*4+2] - acc1[q*4+2],
                            acc2[q*4+3] - acc1[q*4+3]);
    }
}

// ---------------------------------------------------------------------------
// K3: approximate kNN via split-bf16 MFMA, selecting a top-32 superset.
// Block = 64 rows of one batch, 4 waves; wave owns 16 rows. Loop over
// 64-candidate chunks: stage B hi/lo (full 64 elems/point!) in LDS, 6 MFMAs
// per 16x16 tile, write dist tile to per-wave LDS, ballot-insertion top-32.
// ---------------------------------------------------------------------------
__global__ void __launch_bounds__(256) k_knn32(
        const ushort* __restrict__ xh, const ushort* __restrict__ xl,
        const float* __restrict__ sq, int* __restrict__ knn32) {
    __shared__ ushort Bh[64][72];     // +8 pad: bank-spread for b128 frag reads
    __shared__ ushort Bl[64][72];
    __shared__ float dsq[64];
    __shared__ float dw[4][16][68];   // per-wave dist tile, padded

    int b  = blockIdx.x >> 6;
    int r0 = (blockIdx.x & 63) << 6;
    int tid = threadIdx.x;
    int lane = tid & 63;
    int w = tid >> 6;
    int col = lane & 15;
    int quad = lane >> 4;

    // A fragments (chunk-invariant): row = r0 + 16w + col, k = quad*8 + j
    size_t arow = ((size_t)(b * NPTS + r0 + (w << 4) + col)) << 6;
    short8 ah0 = *(const short8*)(xh + arow + quad * 8);
    short8 ah1 = *(const short8*)(xh + arow + 32 + quad * 8);
    short8 al0 = *(const short8*)(xl + arow + quad * 8);
    short8 al1 = *(const short8*)(xl + arow + 32 + quad * 8);

    float dl[16]; int il[16]; float tau[16];
    #pragma unroll
    for (int r = 0; r < 16; ++r) { dl[r] = FLT_MAX; il[r] = 0; tau[r] = FLT_MAX; }

    const ushort* xhb = xh + (((size_t)b * NPTS) << 6);
    const ushort* xlb = xl + (((size_t)b * NPTS) << 6);
    int spt = tid >> 2, seg = tid & 3;

    for (int chunk = 0; chunk < 64; ++chunk) {
        int m0 = chunk << 6;
        __syncthreads();   // prior-iter dw readers done before restage
        {
            const uint4* gh = (const uint4*)(xhb + ((size_t)(m0 + spt) << 6));
            const uint4* gl = (const uint4*)(xlb + ((size_t)(m0 + spt) << 6));
            uint4 vh0 = gh[seg],     vl0 = gl[seg];
            uint4 vh1 = gh[seg + 4], vl1 = gl[seg + 4];
            *(uint4*)&Bh[spt][seg * 8]      = vh0;
            *(uint4*)&Bh[spt][32 + seg * 8] = vh1;
            *(uint4*)&Bl[spt][seg * 8]      = vl0;
            *(uint4*)&Bl[spt][32 + seg * 8] = vl1;
        }
        if (tid < 64) dsq[tid] = sq[b * NPTS + m0 + tid];
        __syncthreads();

        #pragma unroll
        for (int t = 0; t < 4; ++t) {
            int bp = (t << 4) + col;
            short8 bh0 = *(const short8*)&Bh[bp][quad * 8];
            short8 bh1 = *(const short8*)&Bh[bp][32 + quad * 8];
            short8 bl0 = *(const short8*)&Bl[bp][quad * 8];
            short8 bl1 = *(const short8*)&Bl[bp][32 + quad * 8];
            float4v acc = {0.f, 0.f, 0.f, 0.f};
            acc = __builtin_amdgcn_mfma_f32_16x16x32_bf16(ah0, bh0, acc, 0, 0, 0);
            acc = __builtin_amdgcn_mfma_f32_16x16x32_bf16(ah1, bh1, acc, 0, 0, 0);
            acc = __builtin_amdgcn_mfma_f32_16x16x32_bf16(ah0, bl0, acc, 0, 0, 0);
            acc = __builtin_amdgcn_mfma_f32_16x16x32_bf16(ah1, bl1, acc, 0, 0, 0);
            acc = __builtin_amdgcn_mfma_f32_16x16x32_bf16(al0, bh0, acc, 0, 0, 0);
            acc = __builtin_amdgcn_mfma_f32_16x16x32_bf16(al1, bh1, acc, 0, 0, 0);
            float sc = dsq[bp];
            #pragma unroll
            for (int r = 0; r < 4; ++r)
                dw[w][(quad << 2) + r][(t << 4) + col] = fmaf(-2.f, acc[r], sc);
        }
        __syncthreads();   // dw visible; B-frag reads drained before next stage

        int gi = m0 + lane;
        #pragma unroll
        for (int r = 0; r < 16; ++r) {
            float d = dw[w][r][lane];
            unsigned long long mask = __ballot(d < tau[r]);
            while (mask) {
                int s = __ffsll(mask) - 1;
                float ds = __shfl(d, s);
                int   is = __shfl(gi, s);
                unsigned long long gt = __ballot(ds < dl[r]);
                int pos = __ffsll(gt) - 1;            // <= 31 since ds < tau
                float pd = __shfl_up(dl[r], 1);
                int   pi = __shfl_up(il[r], 1);
                if (lane >= pos && lane < KSEL) {
                    if (lane == pos) { dl[r] = ds; il[r] = is; }
                    else             { dl[r] = pd; il[r] = pi; }
                }
                tau[r] = __shfl(dl[r], KSEL - 1);
                mask &= ~(1ull << s);
                mask &= __ballot(d < tau[r]);
            }
        }
    }
    #pragma unroll
    for (int r = 0; r < 16; ++r)
        if (lane < KSEL)
            knn32[((size_t)(b * NPTS + r0 + (w << 4) + r)) * KSEL + lane] = il[r];
}

// ---------------------------------------------------------------------------
// K3b: exact fp32 refinement — one wave per row; lanes 0..31 hold the 32
// candidates, recompute exact fp32 distances, rank lexicographically
// (dist, idx) to match np's lower-index-first tie rule, emit top-20 set.
// ---------------------------------------------------------------------------
__global__ void __launch_bounds__(256) k_refine(
        const float* __restrict__ xt, const float* __restrict__ sq,
        const int* __restrict__ knn32, int* __restrict__ idx20) {
    int wid = (blockIdx.x << 2) + (threadIdx.x >> 6);  // row id [0, B*N)
    int lane = threadIdx.x & 63;
    int b = wid >> 12;
    int cand = knn32[(size_t)wid * KSEL + (lane & (KSEL - 1))];
    const float4* xc = (const float4*)(xt + ((size_t)(b * NPTS + cand) << 6));
    const float4* xr = (const float4*)(xt + ((size_t)wid << 6));
    float acc = 0.f;
    #pragma unroll
    for (int q = 0; q < 16; ++q) {
        float4 a = xr[q], c = xc[q];
        acc = fmaf(a.x, c.x, acc); acc = fmaf(a.y, c.y, acc);
        acc = fmaf(a.z, c.z, acc); acc = fmaf(a.w, c.w, acc);
    }
    float d = fmaf(-2.f, acc, sq[b * NPTS + cand]);
    int rank = 0;
    #pragma unroll
    for (int j = 0; j < KSEL; ++j) {
        float dj = __shfl(d, j);
        int   cj = __shfl(cand, j);
        rank += ((dj < d) || (dj == d && cj < cand)) ? 1 : 0;
    }
    if (lane < KSEL && rank < KNN)
        idx20[(size_t)wid * KNN + rank] = cand;
}

// ---------------------------------------------------------------------------
// K4: gather p columns per neighbor; per-(b,n) max/min/sum/sumsq over k;
// write tmax/tmin = (max/min_k p[idx]) + z; accumulate channel sums.
// ---------------------------------------------------------------------------
__global__ void k_gather(const float* __restrict__ pt, const float* __restrict__ zt,
                         const int* __restrict__ idxin,
                         float* __restrict__ tmax, float* __restrict__ tmin,
                         float* __restrict__ S1, float* __restrict__ S2) {
    __shared__ float red1[4][64];
    __shared__ float red2[4][64];
    int b  = blockIdx.x >> 6;
    int n0 = (blockIdx.x & 63) << 6;
    int lane = threadIdx.x & 63;
    int w = threadIdx.x >> 6;
    float cs1 = 0.f, cs2 = 0.f;
    for (int i = 0; i < 16; ++i) {
        int n = n0 + (w << 4) + i;
        int base = b * NPTS + n;
        int ibase = __builtin_amdgcn_readfirstlane(base * KNN);
        const int* ip = idxin + ibase;
        float mx = -FLT_MAX, mn = FLT_MAX, s1 = 0.f, s2 = 0.f;
        #pragma unroll
        for (int k = 0; k < KNN; ++k) {
            int colp = ip[k];                              // SGPR
            float v = pt[(((size_t)(b * NPTS + colp)) << 6) + lane]; // coalesced
            mx = fmaxf(mx, v); mn = fminf(mn, v);
            s1 += v; s2 = fmaf(v, v, s2);
        }
        float z = zt[(((size_t)base) << 6) + lane];
        tmax[(((size_t)base) << 6) + lane] = mx + z;
        tmin[(((size_t)base) << 6) + lane] = mn + z;
        cs1 += s1 + (float)KNN * z;
        cs2 += s2 + 2.f * z * s1 + (float)KNN * z * z;
    }
    red1[w][lane] = cs1;
    red2[w][lane] = cs2;
    __syncthreads();
    if (threadIdx.x < 64) {
        float t1 = red1[0][lane] + red1[1][lane] + red1[2][lane] + red1[3][lane];
        float t2 = red2[0][lane] + red2[1][lane] + red2[2][lane] + red2[3][lane];
        atomicAdd(&S1[lane], t1);
        atomicAdd(&S2[lane], t2);
    }
}

// ---------------------------------------------------------------------------
// K5: finalize BN stats, affine + LeakyReLU, transpose to out [B,64,N].
// ---------------------------------------------------------------------------
__global__ void k_final(const float* __restrict__ tmax, const float* __restrict__ tmin,
                        const float* __restrict__ S1, const float* __restrict__ S2,
                        const float* __restrict__ gamma, const float* __restrict__ beta,
                        float* __restrict__ out) {
    __shared__ float smx[64][65];
    __shared__ float smn[64][65];
    int b  = blockIdx.x >> 6;
    int n0 = (blockIdx.x & 63) << 6;
    int lane = threadIdx.x & 63;
    int w = threadIdx.x >> 6;
    #pragma unroll
    for (int i = 0; i < 16; ++i) {
        int nl = (i << 2) + w;
        size_t off = (((size_t)(b * NPTS + n0 + nl)) << 6) + lane;
        smx[nl][lane] = tmax[off];
        smn[nl][lane] = tmin[off];
    }
    __syncthreads();
    const float inv_cnt = 1.0f / ((float)BATCH * NPTS * KNN);
    #pragma unroll
    for (int i = 0; i < 16; ++i) {
        int o = (i << 2) + w;
        float s1 = S1[o], s2 = S2[o];
        float mean = s1 * inv_cnt;
        float var = fmaf(-mean, mean, s2 * inv_cnt);
        float rs = rsqrtf(var + BN_EPS);
        float sc = gamma[o] * rs;
        float sh = beta[o] - mean * sc;
        float tv = (sc >= 0.f) ? smx[lane][o] : smn[lane][o];
        float y = fmaf(tv, sc, sh);
        y = (y >= 0.f) ? y : NEG_SLOPE * y;
        out[((size_t)(b * 64 + o)) * NPTS + n0 + lane] = y;
    }
}

// ---------------------------------------------------------------------------
extern "C" void kernel_launch(void* const* d_in, const int* in_sizes, int n_in,
                              void* d_out, int out_size, void* d_ws, size_t ws_size,
                              hipStream_t stream) {
    const float* x     = (const float*)d_in[0];   // [8,64,4096]
    const float* W     = (const float*)d_in[1];   // [64,128]
    const float* gamma = (const float*)d_in[2];   // [64]
    const float* beta  = (const float*)d_in[3];   // [64]
    float* out = (float*)d_out;                   // [8,64,4096]

    float* ws = (float*)d_ws;
    const size_t SECT = (size_t)BATCH * NPTS * 64;      // 2,097,152
    float*  xt    = ws;                                  // [0, SECT)
    float*  pt    = ws + SECT;
    float*  zt    = ws + 2 * SECT;
    float*  sq    = ws + 3 * SECT;                       // 32768
    float*  S1    = ws + 3 * SECT + 32768;               // 64
    float*  S2    = S1 + 64;
    int*    idx20 = (int*)(ws + 3 * SECT + 32768 + 128); // 655,360 ints
    float*  uA    = ws + 3 * SECT + 32768 + 128 + 655360;
    // union region: {xh, xl, knn32} live k_prep..k_refine; {tmx, tmn} after
    ushort* xh    = (ushort*)uA;                         // SECT ushorts
    ushort* xl    = (ushort*)(uA + SECT / 2);            // SECT ushorts
    int*    knn32 = (int*)(uA + SECT);                   // SECT/2 ints
    float*  tmx   = uA;                                  // SECT floats
    float*  tmn   = uA + SECT;                           // SECT floats
    // peak: 3*SECT + 33k + 655k + 2*SECT floats ~= 44.7 MB

    hipMemsetAsync(S1, 0, 2 * 64 * sizeof(float), stream);
    k_prep  <<<dim3((BATCH * NPTS) / 256), dim3(256), 0, stream>>>(x, xt, xh, xl, sq);
    k_pz    <<<dim3(BATCH * (NPTS / 64)), dim3(256), 0, stream>>>(xt, W, pt, zt);
    k_knn32 <<<dim3(BATCH * (NPTS / 64)), dim3(256), 0, stream>>>(xh, xl, sq, knn32);
    k_refine<<<dim3((BATCH * NPTS) / 4), dim3(256), 0, stream>>>(xt, sq, knn32, idx20);
    k_gather<<<dim3(BATCH * (NPTS / 64)), dim3(256), 0, stream>>>(pt, zt, idx20, tmx, tmn, S1, S2);
    k_final <<<dim3(BATCH * (NPTS / 64)), dim3(256), 0, stream>>>(tmx, tmn, S1, S2, gamma, beta, out);
}

// Round 4
// 687.539 us; speedup vs baseline: 1.3953x; 1.2876x over previous
//
#include <hip/hip_runtime.h>
#include <hip/hip_bf16.h>
#include <float.h>

#define BATCH 8
#define CDIM 64
#define NPTS 4096
#define KNN 20
#define KSEL 32
#define BN_EPS 1e-5f
#define NEG_SLOPE 0.2f

typedef __attribute__((ext_vector_type(8))) short short8;
typedef __attribute__((ext_vector_type(4))) float float4v;
typedef unsigned short ushort;
typedef unsigned int uint;

__device__ __forceinline__ ushort f2bf(float f) {
    uint u = __float_as_uint(f);
    u += 0x7FFF + ((u >> 16) & 1);            // round-to-nearest-even
    return (ushort)(u >> 16);
}
__device__ __forceinline__ float bf2f(ushort h) {
    return __uint_as_float(((uint)h) << 16);
}

// cheap cross-lane primitives (avoid ds_permute):
__device__ __forceinline__ float dpp_shr1_f(float x) {   // lane i <- lane i-1
    int xi = __float_as_int(x);
    return __int_as_float(__builtin_amdgcn_update_dpp(xi, xi, 0x138, 0xF, 0xF, false));
}
__device__ __forceinline__ int dpp_shr1_i(int x) {
    return __builtin_amdgcn_update_dpp(x, x, 0x138, 0xF, 0xF, false);
}
__device__ __forceinline__ float rl_f(float v, int l) {  // readlane broadcast
    return __int_as_float(__builtin_amdgcn_readlane(__float_as_int(v), l));
}

// ---------------------------------------------------------------------------
// K1: x [B,C,N] -> xt [B,N,64] fp32, xh/xl [B,N,64] bf16 hi/lo split,
//     sq[b,n] = sum_c x^2 (fp32)
// ---------------------------------------------------------------------------
__global__ void k_prep(const float* __restrict__ x,
                       float* __restrict__ xt,
                       ushort* __restrict__ xh,
                       ushort* __restrict__ xl,
                       float* __restrict__ sq) {
    int gid = blockIdx.x * 256 + threadIdx.x;     // [0, B*N)
    int b = gid >> 12;
    int n = gid & (NPTS - 1);
    const float* xb = x + (size_t)b * CDIM * NPTS + n;
    float acc = 0.f;
    float4* xtv = (float4*)(xt + ((size_t)gid << 6));
    uint2* xhp = (uint2*)(xh + ((size_t)gid << 6));
    uint2* xlp = (uint2*)(xl + ((size_t)gid << 6));
    #pragma unroll
    for (int q = 0; q < 16; ++q) {
        float v[4];
        ushort h[4], l[4];
        #pragma unroll
        for (int j = 0; j < 4; ++j) {
            float t = xb[(q * 4 + j) * NPTS];     // coalesced across n
            v[j] = t;
            acc = fmaf(t, t, acc);
            h[j] = f2bf(t);
            l[j] = f2bf(t - bf2f(h[j]));
        }
        xtv[q] = make_float4(v[0], v[1], v[2], v[3]);
        uint2 ph, pl;
        ph.x = (uint)h[0] | ((uint)h[1] << 16);
        ph.y = (uint)h[2] | ((uint)h[3] << 16);
        pl.x = (uint)l[0] | ((uint)l[1] << 16);
        pl.y = (uint)l[2] | ((uint)l[3] << 16);
        xhp[q] = ph;
        xlp[q] = pl;
    }
    sq[gid] = acc;
}

// ---------------------------------------------------------------------------
// K2: p = W1 @ x, z = (W2-W1) @ x, stored transposed: pt/zt [B,N,64]
// ---------------------------------------------------------------------------
__global__ void k_pz(const float* __restrict__ xt, const float* __restrict__ W,
                     float* __restrict__ pt, float* __restrict__ zt) {
    int b  = blockIdx.x >> 6;
    int n0 = (blockIdx.x & 63) << 6;
    int lane = threadIdx.x & 63;
    int w = threadIdx.x >> 6;
    int n = n0 + lane;
    size_t rowoff = ((size_t)(b * NPTS + n)) << 6;
    const float4* xrow = (const float4*)(xt + rowoff);
    float acc1[16], acc2[16];
    #pragma unroll
    for (int i = 0; i < 16; ++i) { acc1[i] = 0.f; acc2[i] = 0.f; }
    #pragma unroll
    for (int cg = 0; cg < 4; ++cg) {
        float xv[16];
        #pragma unroll
        for (int q = 0; q < 4; ++q) {
            float4 t = xrow[cg * 4 + q];
            xv[q*4] = t.x; xv[q*4+1] = t.y; xv[q*4+2] = t.z; xv[q*4+3] = t.w;
        }
        #pragma unroll
        for (int oi = 0; oi < 16; ++oi) {
            int o = (w << 4) + oi;
            const float* wr = W + o * 128 + cg * 16;
            float a1 = acc1[oi], a2 = acc2[oi];
            #pragma unroll
            for (int j = 0; j < 16; ++j) {
                a1 = fmaf(wr[j],      xv[j], a1);
                a2 = fmaf(wr[64 + j], xv[j], a2);
            }
            acc1[oi] = a1; acc2[oi] = a2;
        }
    }
    float4* pv = (float4*)(pt + rowoff + (w << 4));
    float4* zv = (float4*)(zt + rowoff + (w << 4));
    #pragma unroll
    for (int q = 0; q < 4; ++q) {
        pv[q] = make_float4(acc1[q*4], acc1[q*4+1], acc1[q*4+2], acc1[q*4+3]);
        zv[q] = make_float4(acc2[q*4]   - acc1[q*4],
                            acc2[q*4+1] - acc1[q*4+1],
                            acc2[q*4+2] - acc1[q*4+2],
                            acc2[q*4+3] - acc1[q*4+3]);
    }
}

// ---------------------------------------------------------------------------
// K3: approximate kNN via split-bf16 MFMA, selecting a top-32 superset.
// v2: DPP/readlane insertion (no ds_permute), register double-buffered
// staging, 2 barriers/chunk (dw is per-wave private), batched dw preload.
// ---------------------------------------------------------------------------
__global__ void __launch_bounds__(256) k_knn32(
        const ushort* __restrict__ xh, const ushort* __restrict__ xl,
        const float* __restrict__ sq, int* __restrict__ knn32) {
    __shared__ ushort Bh[64][72];     // +8 pad
    __shared__ ushort Bl[64][72];
    __shared__ float dsq[64];
    __shared__ float dw[4][16][68];   // per-wave dist tile, padded

    int b  = blockIdx.x >> 6;
    int r0 = (blockIdx.x & 63) << 6;
    int tid = threadIdx.x;
    int lane = tid & 63;
    int w = tid >> 6;
    int col = lane & 15;
    int quad = lane >> 4;

    // A fragments (chunk-invariant): row = r0 + 16w + col, k = quad*8 + j
    size_t arow = ((size_t)(b * NPTS + r0 + (w << 4) + col)) << 6;
    short8 ah0 = *(const short8*)(xh + arow + quad * 8);
    short8 ah1 = *(const short8*)(xh + arow + 32 + quad * 8);
    short8 al0 = *(const short8*)(xl + arow + quad * 8);
    short8 al1 = *(const short8*)(xl + arow + 32 + quad * 8);

    float dl[16]; int il[16]; float tau[16];
    #pragma unroll
    for (int r = 0; r < 16; ++r) { dl[r] = FLT_MAX; il[r] = 0; tau[r] = FLT_MAX; }

    const ushort* xhb = xh + (((size_t)b * NPTS) << 6);
    const ushort* xlb = xl + (((size_t)b * NPTS) << 6);
    const float* sqb = sq + b * NPTS;
    int spt = tid >> 2, seg = tid & 3;

    // prefetch chunk 0 into registers
    uint4 vh0, vh1, vl0, vl1;
    float sqpre;
    {
        const uint4* gh = (const uint4*)(xhb + ((size_t)spt << 6));
        const uint4* gl = (const uint4*)(xlb + ((size_t)spt << 6));
        vh0 = gh[seg]; vh1 = gh[seg + 4];
        vl0 = gl[seg]; vl1 = gl[seg + 4];
        sqpre = sqb[lane];           // only tid<64's value is used
    }

    for (int chunk = 0; chunk < 64; ++chunk) {
        int m0 = chunk << 6;
        __syncthreads();   // prior-iter B-frag reads done before restage
        *(uint4*)&Bh[spt][seg * 8]      = vh0;
        *(uint4*)&Bh[spt][32 + seg * 8] = vh1;
        *(uint4*)&Bl[spt][seg * 8]      = vl0;
        *(uint4*)&Bl[spt][32 + seg * 8] = vl1;
        if (tid < 64) dsq[tid] = sqpre;
        __syncthreads();   // B staged

        // issue next chunk's loads now; consumed at next iteration's store
        if (chunk < 63) {
            int m1 = m0 + 64;
            const uint4* gh = (const uint4*)(xhb + ((size_t)(m1 + spt) << 6));
            const uint4* gl = (const uint4*)(xlb + ((size_t)(m1 + spt) << 6));
            vh0 = gh[seg]; vh1 = gh[seg + 4];
            vl0 = gl[seg]; vl1 = gl[seg + 4];
            sqpre = sqb[m1 + lane];
        }

        #pragma unroll
        for (int t = 0; t < 4; ++t) {
            int bp = (t << 4) + col;
            short8 bh0 = *(const short8*)&Bh[bp][quad * 8];
            short8 bh1 = *(const short8*)&Bh[bp][32 + quad * 8];
            short8 bl0 = *(const short8*)&Bl[bp][quad * 8];
            short8 bl1 = *(const short8*)&Bl[bp][32 + quad * 8];
            float4v acc = {0.f, 0.f, 0.f, 0.f};
            acc = __builtin_amdgcn_mfma_f32_16x16x32_bf16(ah0, bh0, acc, 0, 0, 0);
            acc = __builtin_amdgcn_mfma_f32_16x16x32_bf16(ah1, bh1, acc, 0, 0, 0);
            acc = __builtin_amdgcn_mfma_f32_16x16x32_bf16(ah0, bl0, acc, 0, 0, 0);
            acc = __builtin_amdgcn_mfma_f32_16x16x32_bf16(ah1, bl1, acc, 0, 0, 0);
            acc = __builtin_amdgcn_mfma_f32_16x16x32_bf16(al0, bh0, acc, 0, 0, 0);
            acc = __builtin_amdgcn_mfma_f32_16x16x32_bf16(al1, bh1, acc, 0, 0, 0);
            float sc = dsq[bp];
            #pragma unroll
            for (int r = 0; r < 4; ++r)
                dw[w][(quad << 2) + r][(t << 4) + col] = fmaf(-2.f, acc[r], sc);
        }
        // dw is per-wave private: no barrier needed, lgkmcnt ordering suffices

        float dvals[16];
        #pragma unroll
        for (int r = 0; r < 16; ++r) dvals[r] = dw[w][r][lane];

        #pragma unroll
        for (int r = 0; r < 16; ++r) {
            float d = dvals[r];
            unsigned long long mask = __ballot(d < tau[r]);
            while (mask) {
                int s = __ffsll((long long)mask) - 1;      // uniform
                float ds = rl_f(d, s);                     // readlane (scalar)
                int   is = m0 + s;                         // scalar arithmetic
                unsigned long long gt = __ballot(ds < dl[r]);
                int pos = __ffsll((long long)gt) - 1;      // insertion point
                float pd = dpp_shr1_f(dl[r]);              // single-VALU shift
                int   pi = dpp_shr1_i(il[r]);
                if (lane >= pos && lane < KSEL) {
                    dl[r] = (lane == pos) ? ds : pd;
                    il[r] = (lane == pos) ? is : pi;
                }
                tau[r] = rl_f(dl[r], KSEL - 1);
                mask &= (mask - 1);
                mask &= __ballot(d < tau[r]);
            }
        }
    }
    #pragma unroll
    for (int r = 0; r < 16; ++r)
        if (lane < KSEL)
            knn32[((size_t)(b * NPTS + r0 + (w << 4) + r)) * KSEL + lane] = il[r];
}

// ---------------------------------------------------------------------------
// K3b: exact fp32 refinement — one wave per row; lanes 0..31 hold the 32
// candidates, recompute exact fp32 distances, rank lexicographically
// (dist, idx) to match np's lower-index-first tie rule, emit top-20 set.
// ---------------------------------------------------------------------------
__global__ void __launch_bounds__(256) k_refine(
        const float* __restrict__ xt, const float* __restrict__ sq,
        const int* __restrict__ knn32, int* __restrict__ idx20) {
    int wid = (blockIdx.x << 2) + (threadIdx.x >> 6);  // row id [0, B*N)
    int lane = threadIdx.x & 63;
    int b = wid >> 12;
    int cand = knn32[(size_t)wid * KSEL + (lane & (KSEL - 1))];
    const float4* xc = (const float4*)(xt + ((size_t)(b * NPTS + cand) << 6));
    const float4* xr = (const float4*)(xt + ((size_t)wid << 6));
    float acc = 0.f;
    #pragma unroll
    for (int q = 0; q < 16; ++q) {
        float4 a = xr[q], c = xc[q];
        acc = fmaf(a.x, c.x, acc); acc = fmaf(a.y, c.y, acc);
        acc = fmaf(a.z, c.z, acc); acc = fmaf(a.w, c.w, acc);
    }
    float d = fmaf(-2.f, acc, sq[b * NPTS + cand]);
    int rank = 0;
    #pragma unroll
    for (int j = 0; j < KSEL; ++j) {
        float dj = __shfl(d, j);
        int   cj = __shfl(cand, j);
        rank += ((dj < d) || (dj == d && cj < cand)) ? 1 : 0;
    }
    if (lane < KSEL && rank < KNN)
        idx20[(size_t)wid * KNN + rank] = cand;
}

// ---------------------------------------------------------------------------
// K4: gather p columns per neighbor; per-(b,n) max/min/sum/sumsq over k;
// write tmax/tmin = (max/min_k p[idx]) + z; accumulate channel sums.
// ---------------------------------------------------------------------------
__global__ void k_gather(const float* __restrict__ pt, const float* __restrict__ zt,
                         const int* __restrict__ idxin,
                         float* __restrict__ tmax, float* __restrict__ tmin,
                         float* __restrict__ S1, float* __restrict__ S2) {
    __shared__ float red1[4][64];
    __shared__ float red2[4][64];
    int b  = blockIdx.x >> 6;
    int n0 = (blockIdx.x & 63) << 6;
    int lane = threadIdx.x & 63;
    int w = threadIdx.x >> 6;
    float cs1 = 0.f, cs2 = 0.f;
    for (int i = 0; i < 16; ++i) {
        int n = n0 + (w << 4) + i;
        int base = b * NPTS + n;
        int ibase = __builtin_amdgcn_readfirstlane(base * KNN);
        const int* ip = idxin + ibase;
        float mx = -FLT_MAX, mn = FLT_MAX, s1 = 0.f, s2 = 0.f;
        #pragma unroll
        for (int k = 0; k < KNN; ++k) {
            int colp = ip[k];                              // SGPR
            float v = pt[(((size_t)(b * NPTS + colp)) << 6) + lane]; // coalesced
            mx = fmaxf(mx, v); mn = fminf(mn, v);
            s1 += v; s2 = fmaf(v, v, s2);
        }
        float z = zt[(((size_t)base) << 6) + lane];
        tmax[(((size_t)base) << 6) + lane] = mx + z;
        tmin[(((size_t)base) << 6) + lane] = mn + z;
        cs1 += s1 + (float)KNN * z;
        cs2 += s2 + 2.f * z * s1 + (float)KNN * z * z;
    }
    red1[w][lane] = cs1;
    red2[w][lane] = cs2;
    __syncthreads();
    if (threadIdx.x < 64) {
        float t1 = red1[0][lane] + red1[1][lane] + red1[2][lane] + red1[3][lane];
        float t2 = red2[0][lane] + red2[1][lane] + red2[2][lane] + red2[3][lane];
        atomicAdd(&S1[lane], t1);
        atomicAdd(&S2[lane], t2);
    }
}

// ---------------------------------------------------------------------------
// K5: finalize BN stats, affine + LeakyReLU, transpose to out [B,64,N].
// ---------------------------------------------------------------------------
__global__ void k_final(const float* __restrict__ tmax, const float* __restrict__ tmin,
                        const float* __restrict__ S1, const float* __restrict__ S2,
                        const float* __restrict__ gamma, const float* __restrict__ beta,
                        float* __restrict__ out) {
    __shared__ float smx[64][65];
    __shared__ float smn[64][65];
    int b  = blockIdx.x >> 6;
    int n0 = (blockIdx.x & 63) << 6;
    int lane = threadIdx.x & 63;
    int w = threadIdx.x >> 6;
    #pragma unroll
    for (int i = 0; i < 16; ++i) {
        int nl = (i << 2) + w;
        size_t off = (((size_t)(b * NPTS + n0 + nl)) << 6) + lane;
        smx[nl][lane] = tmax[off];
        smn[nl][lane] = tmin[off];
    }
    __syncthreads();
    const float inv_cnt = 1.0f / ((float)BATCH * NPTS * KNN);
    #pragma unroll
    for (int i = 0; i < 16; ++i) {
        int o = (i << 2) + w;
        float s1 = S1[o], s2 = S2[o];
        float mean = s1 * inv_cnt;
        float var = fmaf(-mean, mean, s2 * inv_cnt);
        float rs = rsqrtf(var + BN_EPS);
        float sc = gamma[o] * rs;
        float sh = beta[o] - mean * sc;
        float tv = (sc >= 0.f) ? smx[lane][o] : smn[lane][o];
        float y = fmaf(tv, sc, sh);
        y = (y >= 0.f) ? y : NEG_SLOPE * y;
        out[((size_t)(b * 64 + o)) * NPTS + n0 + lane] = y;
    }
}

// ---------------------------------------------------------------------------
extern "C" void kernel_launch(void* const* d_in, const int* in_sizes, int n_in,
                              void* d_out, int out_size, void* d_ws, size_t ws_size,
                              hipStream_t stream) {
    const float* x     = (const float*)d_in[0];   // [8,64,4096]
    const float* W     = (const float*)d_in[1];   // [64,128]
    const float* gamma = (const float*)d_in[2];   // [64]
    const float* beta  = (const float*)d_in[3];   // [64]
    float* out = (float*)d_out;                   // [8,64,4096]

    float* ws = (float*)d_ws;
    const size_t SECT = (size_t)BATCH * NPTS * 64;      // 2,097,152
    float*  xt    = ws;                                  // [0, SECT)
    float*  pt    = ws + SECT;
    float*  zt    = ws + 2 * SECT;
    float*  sq    = ws + 3 * SECT;                       // 32768
    float*  S1    = ws + 3 * SECT + 32768;               // 64
    float*  S2    = S1 + 64;
    int*    idx20 = (int*)(ws + 3 * SECT + 32768 + 128); // 655,360 ints
    float*  uA    = ws + 3 * SECT + 32768 + 128 + 655360;
    // union region: {xh, xl, knn32} live k_prep..k_refine; {tmx, tmn} after
    ushort* xh    = (ushort*)uA;                         // SECT ushorts
    ushort* xl    = (ushort*)(uA + SECT / 2);            // SECT ushorts
    int*    knn32 = (int*)(uA + SECT);                   // SECT/2 ints
    float*  tmx   = uA;                                  // SECT floats
    float*  tmn   = uA + SECT;                           // SECT floats

    hipMemsetAsync(S1, 0, 2 * 64 * sizeof(float), stream);
    k_prep  <<<dim3((BATCH * NPTS) / 256), dim3(256), 0, stream>>>(x, xt, xh, xl, sq);
    k_pz    <<<dim3(BATCH * (NPTS / 64)), dim3(256), 0, stream>>>(xt, W, pt, zt);
    k_knn32 <<<dim3(BATCH * (NPTS / 64)), dim3(256), 0, stream>>>(xh, xl, sq, knn32);
    k_refine<<<dim3((BATCH * NPTS) / 4), dim3(256), 0, stream>>>(xt, sq, knn32, idx20);
    k_gather<<<dim3(BATCH * (NPTS / 64)), dim3(256), 0, stream>>>(pt, zt, idx20, tmx, tmn, S1, S2);
    k_final <<<dim3(BATCH * (NPTS / 64)), dim3(256), 0, stream>>>(tmx, tmn, S1, S2, gamma, beta, out);
}